// Round 1
// baseline (3055.760 us; speedup 1.0000x reference)
//
#include <hip/hip_runtime.h>
#include <math.h>

#define N_NODES 100000
#define N_EDGES 800000
#define NGRAPH  64

// ---------- helpers ----------
static __device__ __forceinline__ unsigned flip_f(float x) {
  unsigned u = __float_as_uint(x);
  return u ^ ((u & 0x80000000u) ? 0xFFFFFFFFu : 0x80000000u);
}
static __device__ __forceinline__ float unflip_f(unsigned m) {
  unsigned u = m ^ ((m & 0x80000000u) ? 0x80000000u : 0xFFFFFFFFu);
  return __uint_as_float(u);
}

// ---------- CSR build ----------
__global__ void hist_k(const int* __restrict__ dst, int* __restrict__ cnt) {
  int e = blockIdx.x * 256 + threadIdx.x;
  if (e < N_EDGES) atomicAdd(&cnt[dst[e]], 1);
}

__global__ void dinv_k(const int* __restrict__ cnt, float* __restrict__ dinv) {
  int i = blockIdx.x * 256 + threadIdx.x;
  if (i < N_NODES) dinv[i] = rsqrtf((float)cnt[i] + 1.0f);
}

__global__ void scan_block_k(const int* __restrict__ cnt, int* __restrict__ rs,
                             int* __restrict__ bsum) {
  __shared__ int s[256];
  int t = threadIdx.x, i = blockIdx.x * 256 + t;
  int v = (i < N_NODES) ? cnt[i] : 0;
  s[t] = v; __syncthreads();
  for (int off = 1; off < 256; off <<= 1) {
    int a = (t >= off) ? s[t - off] : 0;
    __syncthreads();
    s[t] += a;
    __syncthreads();
  }
  if (i < N_NODES) rs[i] = s[t] - v;       // exclusive
  if (t == 255) bsum[blockIdx.x] = s[255]; // block total
}

__global__ void scan_bsum_k(int* __restrict__ bsum, int nb) {
  __shared__ int s[512];
  int t = threadIdx.x;
  int v = (t < nb) ? bsum[t] : 0;
  s[t] = v; __syncthreads();
  for (int off = 1; off < 512; off <<= 1) {
    int a = (t >= off) ? s[t - off] : 0;
    __syncthreads();
    s[t] += a;
    __syncthreads();
  }
  if (t < nb) bsum[t] = s[t] - v;          // exclusive
}

__global__ void scan_add_k(int* __restrict__ rs, int* __restrict__ cursor,
                           const int* __restrict__ bsum) {
  int i = blockIdx.x * 256 + threadIdx.x;
  if (i < N_NODES) {
    int r = rs[i] + bsum[i >> 8];
    rs[i] = r;
    cursor[i] = r;
  }
}

__global__ void build_k(const int* __restrict__ src, const int* __restrict__ dst,
                        int* __restrict__ cursor, int* __restrict__ srcs) {
  int e = blockIdx.x * 256 + threadIdx.x;
  if (e < N_EDGES) {
    int d = dst[e];
    int p = atomicAdd(&cursor[d], 1);
    srcs[p] = src[e];
  }
}

__global__ void graph_starts_k(const int* __restrict__ batch, int* __restrict__ gstart) {
  int g = threadIdx.x;
  if (g > NGRAPH) return;
  if (g == NGRAPH) { gstart[NGRAPH] = N_NODES; return; }
  int lo = 0, hi = N_NODES;
  while (lo < hi) {
    int mid = (lo + hi) >> 1;
    if (batch[mid] < g) lo = mid + 1; else hi = mid;
  }
  gstart[g] = lo;
}

// ---------- GEMM: C = epilogue(A[M,K] @ B[K,F]) ----------
// epilogue: v = acc (+bias); if relu v=max(v,0); (+add1) (+add2)
__global__ __launch_bounds__(256)
void gemm_kernel(const float* __restrict__ A, const float* __restrict__ B,
                 const float* __restrict__ bias, const float* __restrict__ add1,
                 const float* __restrict__ add2, float* __restrict__ C,
                 int M, int K, int F, int relu) {
  __shared__ float As[16][65];
  __shared__ float Bs[16][65];
  const int tid = threadIdx.x;
  const int tx = tid & 15, ty = tid >> 4;
  const int row0 = blockIdx.x * 64;
  const int col0 = blockIdx.y * 64;
  float acc[4][4];
#pragma unroll
  for (int i = 0; i < 4; i++)
#pragma unroll
    for (int j = 0; j < 4; j++) acc[i][j] = 0.f;

  for (int k0 = 0; k0 < K; k0 += 16) {
#pragma unroll
    for (int l = 0; l < 4; l++) {
      int idx = tid + l * 256;
      int m = idx >> 4, k = idx & 15;
      int r = row0 + m;
      As[k][m] = (r < M) ? A[(size_t)r * K + k0 + k] : 0.f;
    }
#pragma unroll
    for (int l = 0; l < 4; l++) {
      int idx = tid + l * 256;
      int k = idx >> 6, n = idx & 63;
      Bs[k][n] = B[(size_t)(k0 + k) * F + col0 + n];
    }
    __syncthreads();
#pragma unroll
    for (int k = 0; k < 16; k++) {
      float a[4], b[4];
#pragma unroll
      for (int i = 0; i < 4; i++) a[i] = As[k][ty * 4 + i];
#pragma unroll
      for (int j = 0; j < 4; j++) b[j] = Bs[k][tx * 4 + j];
#pragma unroll
      for (int i = 0; i < 4; i++)
#pragma unroll
        for (int j = 0; j < 4; j++) acc[i][j] += a[i] * b[j];
    }
    __syncthreads();
  }
#pragma unroll
  for (int i = 0; i < 4; i++) {
    int r = row0 + ty * 4 + i;
    if (r >= M) continue;
#pragma unroll
    for (int j = 0; j < 4; j++) {
      int c = col0 + tx * 4 + j;
      float v = acc[i][j];
      if (bias) v += bias[c];
      if (relu) v = fmaxf(v, 0.f);
      size_t off = (size_t)r * F + c;
      if (add1) v += add1[off];
      if (add2) v += add2[off];
      C[off] = v;
    }
  }
}

// ---------- elementwise: out = a + pe3 (pe tiled 3x over 192) ----------
__global__ void add_pe3_k(const float* __restrict__ a, const float* __restrict__ pe,
                          float* __restrict__ out) {
  int t = blockIdx.x * 256 + threadIdx.x;
  if (t >= N_NODES * 48) return;
  int i = t / 48, c = (t - i * 48) * 4;
  float4 v = *(const float4*)(a + (size_t)i * 192 + c);
  float4 p = *(const float4*)(pe + (size_t)i * 64 + (c & 63));
  v.x += p.x; v.y += p.y; v.z += p.z; v.w += p.w;
  *(float4*)(out + (size_t)i * 192 + c) = v;
}

// ---------- aggregations over CSR (gather form, no float atomics) ----------
template <int F>
__global__ void agg_mpnn_k(const float* __restrict__ x, const int* __restrict__ rowstart,
                           const int* __restrict__ cnt, const int* __restrict__ srcs,
                           float* __restrict__ out) {
  constexpr int F4 = F / 4;
  int t = blockIdx.x * 256 + threadIdx.x;
  if (t >= N_NODES * F4) return;
  int i = t / F4, c = (t - i * F4) * 4;
  float4 acc = make_float4(0.f, 0.f, 0.f, 0.f);
  int e = rowstart[i], e1 = e + cnt[i];
  for (; e < e1; ++e) {
    int s = srcs[e];
    float4 v = *(const float4*)(x + (size_t)s * F + c);
    acc.x += v.x; acc.y += v.y; acc.z += v.z; acc.w += v.w;
  }
  *(float4*)(out + (size_t)i * F + c) = acc;
}

template <int F, bool RELU, bool HAS_BIAS>
__global__ void agg_gcn_k(const float* __restrict__ x, const int* __restrict__ rowstart,
                          const int* __restrict__ cnt, const int* __restrict__ srcs,
                          const float* __restrict__ dinv, const float* __restrict__ bias,
                          float* __restrict__ out) {
  constexpr int F4 = F / 4;
  int t = blockIdx.x * 256 + threadIdx.x;
  if (t >= N_NODES * F4) return;
  int i = t / F4, c = (t - i * F4) * 4;
  float4 acc = make_float4(0.f, 0.f, 0.f, 0.f);
  int e = rowstart[i], e1 = e + cnt[i];
  for (; e < e1; ++e) {
    int s = srcs[e];
    float w = dinv[s];
    float4 v = *(const float4*)(x + (size_t)s * F + c);
    acc.x += w * v.x; acc.y += w * v.y; acc.z += w * v.z; acc.w += w * v.w;
  }
  float di = dinv[i];
  float sw = di * di;
  float4 self = *(const float4*)(x + (size_t)i * F + c);
  float4 r;
  r.x = di * acc.x + sw * self.x;
  r.y = di * acc.y + sw * self.y;
  r.z = di * acc.z + sw * self.z;
  r.w = di * acc.w + sw * self.w;
  if (HAS_BIAS) {
    float4 b = *(const float4*)(bias + c);
    r.x += b.x; r.y += b.y; r.z += b.z; r.w += b.w;
  }
  if (RELU) {
    r.x = fmaxf(r.x, 0.f); r.y = fmaxf(r.y, 0.f);
    r.z = fmaxf(r.z, 0.f); r.w = fmaxf(r.w, 0.f);
  }
  *(float4*)(out + (size_t)i * F + c) = r;
}

// decoder GCN: x-rows come from 64-row table zgW via batch lookup
__global__ void agg_gcn_dec_k(const float* __restrict__ zgW, const int* __restrict__ rowstart,
                              const int* __restrict__ cnt, const int* __restrict__ srcs,
                              const int* __restrict__ batch, const float* __restrict__ dinv,
                              const float* __restrict__ bias, float* __restrict__ out) {
  int t = blockIdx.x * 256 + threadIdx.x;
  if (t >= N_NODES * 48) return;
  int i = t / 48, c = (t - i * 48) * 4;
  float4 acc = make_float4(0.f, 0.f, 0.f, 0.f);
  int e = rowstart[i], e1 = e + cnt[i];
  for (; e < e1; ++e) {
    int s = srcs[e];
    float w = dinv[s];
    float4 v = *(const float4*)(zgW + (size_t)batch[s] * 192 + c);
    acc.x += w * v.x; acc.y += w * v.y; acc.z += w * v.z; acc.w += w * v.w;
  }
  float di = dinv[i];
  float sw = di * di;
  float4 self = *(const float4*)(zgW + (size_t)batch[i] * 192 + c);
  float4 b = *(const float4*)(bias + c);
  float4 r;
  r.x = fmaxf(di * acc.x + sw * self.x + b.x, 0.f);
  r.y = fmaxf(di * acc.y + sw * self.y + b.y, 0.f);
  r.z = fmaxf(di * acc.z + sw * self.z + b.z, 0.f);
  r.w = fmaxf(di * acc.w + sw * self.w + b.w, 0.f);
  *(float4*)(out + (size_t)i * 192 + c) = r;
}

// ---------- segment softmax (per graph, per channel) ----------
__global__ void init_gmax_k(unsigned* __restrict__ gmaxu) {
  int t = blockIdx.x * 256 + threadIdx.x;
  if (t < NGRAPH * 192) gmaxu[t] = 0x007FFFFFu; // flip(-inf)
}

__global__ void seg_max_k(const float* __restrict__ gate, const int* __restrict__ gstart,
                          unsigned* __restrict__ gmaxu) {
  int g = blockIdx.x, f = threadIdx.x;
  int lo = gstart[g], hi = gstart[g + 1];
  int len = hi - lo;
  if (len <= 0) return;
  int per = (len + gridDim.y - 1) / gridDim.y;
  int a = lo + blockIdx.y * per;
  int b = min(a + per, hi);
  if (a >= b) return;
  float m = -INFINITY;
  for (int i = a; i < b; i++) m = fmaxf(m, gate[(size_t)i * 192 + f]);
  atomicMax(&gmaxu[g * 192 + f], flip_f(m));
}

__global__ void seg_sum_k(const float* __restrict__ gate, const float* __restrict__ z,
                          const int* __restrict__ gstart, const unsigned* __restrict__ gmaxu,
                          float* __restrict__ esum, float* __restrict__ znum) {
  int g = blockIdx.x, f = threadIdx.x;
  int lo = gstart[g], hi = gstart[g + 1];
  int len = hi - lo;
  if (len <= 0) return;
  int per = (len + gridDim.y - 1) / gridDim.y;
  int a = lo + blockIdx.y * per;
  int b = min(a + per, hi);
  if (a >= b) return;
  float gm = unflip_f(gmaxu[g * 192 + f]);
  float se = 0.f, sz = 0.f;
  for (int i = a; i < b; i++) {
    float e = expf(gate[(size_t)i * 192 + f] - gm);
    se += e;
    sz += e * z[(size_t)i * 192 + f];
  }
  atomicAdd(&esum[g * 192 + f], se);
  atomicAdd(&znum[g * 192 + f], sz);
}

__global__ void zg_fin_k(const float* __restrict__ znum, const float* __restrict__ esum,
                         float* __restrict__ zg) {
  int t = blockIdx.x * 256 + threadIdx.x;
  if (t >= NGRAPH * 192) return;
  float es = esum[t];
  zg[t] = (es > 0.f) ? znum[t] / es : 0.f;
}

// ---------- launch ----------
extern "C" void kernel_launch(void* const* d_in, const int* in_sizes, int n_in,
                              void* d_out, int out_size, void* d_ws, size_t ws_size,
                              hipStream_t stream) {
  const float* x1 = (const float*)d_in[0];
  const float* x2 = (const float*)d_in[1];
  const float* pe = (const float*)d_in[2];
  const int* ei = (const int*)d_in[3];
  const int* src = ei;
  const int* dst = ei + N_EDGES;
  const int* batch = (const int*)d_in[4];
  const float* Wc  = (const float*)d_in[5];  const float* bc  = (const float*)d_in[6];
  const float* Wmf = (const float*)d_in[7];  const float* bmf = (const float*)d_in[8];
  const float* Wgf = (const float*)d_in[9];  const float* bgf = (const float*)d_in[10];
  const float* Wmc = (const float*)d_in[11]; const float* bmc = (const float*)d_in[12];
  const float* Wgc = (const float*)d_in[13]; const float* bgc = (const float*)d_in[14];
  const float* Wa1 = (const float*)d_in[15]; const float* ba1 = (const float*)d_in[16];
  const float* Wa2 = (const float*)d_in[17]; const float* ba2 = (const float*)d_in[18];
  const float* Wgd = (const float*)d_in[19]; const float* bgd = (const float*)d_in[20];
  const float* Wd1 = (const float*)d_in[21]; const float* bd1 = (const float*)d_in[22];
  const float* Wd2 = (const float*)d_in[23]; const float* bd2 = (const float*)d_in[24];
  const float* Wd3 = (const float*)d_in[25]; const float* bd3 = (const float*)d_in[26];
  float* out = (float*)d_out;

  float* W = (float*)d_ws;
  size_t o = 0;
  float* P0  = W + o; o += (size_t)N_NODES * 192; // x1_res -> z (in place)
  float* P1  = W + o; o += (size_t)N_NODES * 256; // h0 -> h1 -> g1 -> t1
  float* P2  = W + o; o += (size_t)N_NODES * 192; // agg1 -> gate -> t0 -> agg_b -> agg_c
  float* P5a = W + o; o += (size_t)N_NODES * 32;  // aggc
  float* P5b = W + o; o += (size_t)N_NODES * 64;  // c1
  float* P5c = W + o; o += (size_t)N_NODES * 64;  // cagg
  float* dinv = W + o; o += N_NODES;
  unsigned* gmaxu = (unsigned*)(W + o); o += NGRAPH * 192;
  float* esum = W + o; o += NGRAPH * 192;
  float* znum = W + o; o += NGRAPH * 192;
  float* zg   = W + o; o += NGRAPH * 192;
  float* zgW  = W + o; o += NGRAPH * 192;
  int* cnt      = (int*)(W + o); o += N_NODES;
  int* rowstart = (int*)(W + o); o += N_NODES;
  int* cursor   = (int*)(W + o); o += N_NODES;
  int* srcs     = (int*)(W + o); o += N_EDGES;
  int* bsum     = (int*)(W + o); o += 512;
  int* gstart   = (int*)(W + o); o += 80;

  float* P3 = out;                           // d_out lower half: hW -> agg_a -> t2
  float* P4 = out + (size_t)N_NODES * 192;   // d_out upper half: h2 -> z1_res

  const int TB = 256;
  hipMemsetAsync(cnt, 0, N_NODES * sizeof(int), stream);
  hipMemsetAsync(esum, 0, 2 * NGRAPH * 192 * sizeof(float), stream);

  // CSR build (dst-sorted)
  hist_k<<<(N_EDGES + TB - 1) / TB, TB, 0, stream>>>(dst, cnt);
  dinv_k<<<(N_NODES + TB - 1) / TB, TB, 0, stream>>>(cnt, dinv);
  int nb = (N_NODES + 255) / 256;
  scan_block_k<<<nb, 256, 0, stream>>>(cnt, rowstart, bsum);
  scan_bsum_k<<<1, 512, 0, stream>>>(bsum, nb);
  scan_add_k<<<nb, 256, 0, stream>>>(rowstart, cursor, bsum);
  build_k<<<(N_EDGES + TB - 1) / TB, TB, 0, stream>>>(src, dst, cursor, srcs);
  graph_starts_k<<<1, 128, 0, stream>>>(batch, gstart);

  dim3 g192((N_NODES + 63) / 64, 3);
  dim3 g256((N_NODES + 63) / 64, 4);
  dim3 g384((N_NODES + 63) / 64, 6);
  dim3 g64n((N_NODES + 63) / 64, 1);
  int ew192 = (N_NODES * 48 + TB - 1) / TB;

  // ---- encoder ----
  gemm_kernel<<<g192, 256, 0, stream>>>(x1, Wc, bc, nullptr, nullptr, P0, N_NODES, 384, 192, 1);
  add_pe3_k<<<ew192, TB, 0, stream>>>(P0, pe, P1);
  agg_mpnn_k<192><<<ew192, TB, 0, stream>>>(P1, rowstart, cnt, srcs, P2);
  gemm_kernel<<<g256, 256, 0, stream>>>(P2, Wmf, bmf, nullptr, nullptr, P1, N_NODES, 192, 256, 1);
  gemm_kernel<<<g192, 256, 0, stream>>>(P1, Wgf, nullptr, nullptr, nullptr, P3, N_NODES, 256, 192, 0);
  agg_gcn_k<192, true, true><<<ew192, TB, 0, stream>>>(P3, rowstart, cnt, srcs, dinv, bgf, P4);
  agg_mpnn_k<32><<<(N_NODES * 8 + TB - 1) / TB, TB, 0, stream>>>(x2, rowstart, cnt, srcs, P5a);
  gemm_kernel<<<g64n, 256, 0, stream>>>(P5a, Wmc, bmc, nullptr, nullptr, P5b, N_NODES, 32, 64, 1);
  agg_gcn_k<64, false, false><<<(N_NODES * 16 + TB - 1) / TB, TB, 0, stream>>>(P5b, rowstart, cnt, srcs, dinv, nullptr, P5c);
  // z = relu(cagg@Wgc + bgc) + h2 + x1_res  (in place over x1_res)
  gemm_kernel<<<g192, 256, 0, stream>>>(P5c, Wgc, bgc, P4, P0, P0, N_NODES, 64, 192, 1);

  // ---- attention aggregation ----
  gemm_kernel<<<g256, 256, 0, stream>>>(P0, Wa1, ba1, nullptr, nullptr, P1, N_NODES, 192, 256, 1);
  gemm_kernel<<<g192, 256, 0, stream>>>(P1, Wa2, ba2, nullptr, nullptr, P2, N_NODES, 256, 192, 0);
  init_gmax_k<<<(NGRAPH * 192 + TB - 1) / TB, TB, 0, stream>>>(gmaxu);
  dim3 sg(NGRAPH, 16);
  seg_max_k<<<sg, 192, 0, stream>>>(P2, gstart, gmaxu);
  seg_sum_k<<<sg, 192, 0, stream>>>(P2, P0, gstart, gmaxu, esum, znum);
  zg_fin_k<<<(NGRAPH * 192 + TB - 1) / TB, TB, 0, stream>>>(znum, esum, zg);
  dim3 gz(1, 3);
  gemm_kernel<<<gz, 256, 0, stream>>>(zg, Wgd, nullptr, nullptr, nullptr, zgW, NGRAPH, 192, 192, 0);

  // ---- decoder ----
  agg_gcn_dec_k<<<ew192, TB, 0, stream>>>(zgW, rowstart, cnt, srcs, batch, dinv, bgd, P4);
  add_pe3_k<<<ew192, TB, 0, stream>>>(P4, pe, P2);                       // t0
  agg_mpnn_k<192><<<ew192, TB, 0, stream>>>(P2, rowstart, cnt, srcs, P3); // agg_a
  gemm_kernel<<<g192, 256, 0, stream>>>(P3, Wd1, bd1, nullptr, nullptr, P1, N_NODES, 192, 192, 1); // t1
  agg_mpnn_k<192><<<ew192, TB, 0, stream>>>(P1, rowstart, cnt, srcs, P2); // agg_b
  gemm_kernel<<<g192, 256, 0, stream>>>(P2, Wd2, bd2, P4, nullptr, P3, N_NODES, 192, 192, 1); // t2 = relu+z1_res
  agg_mpnn_k<192><<<ew192, TB, 0, stream>>>(P3, rowstart, cnt, srcs, P2); // agg_c
  gemm_kernel<<<g384, 256, 0, stream>>>(P2, Wd3, bd3, nullptr, nullptr, out, N_NODES, 192, 384, 1);
  (void)in_sizes; (void)n_in; (void)out_size; (void)ws_size;
}

// Round 2
// 1911.363 us; speedup vs baseline: 1.5987x; 1.5987x over previous
//
#include <hip/hip_runtime.h>
#include <math.h>

#define N_NODES 100000
#define N_EDGES 800000
#define NGRAPH  64

typedef __attribute__((ext_vector_type(8))) __bf16 bf16x8;
typedef __attribute__((ext_vector_type(4))) float f32x4;

// ---------- helpers ----------
static __device__ __forceinline__ unsigned flip_f(float x) {
  unsigned u = __float_as_uint(x);
  return u ^ ((u & 0x80000000u) ? 0xFFFFFFFFu : 0x80000000u);
}
static __device__ __forceinline__ float unflip_f(unsigned m) {
  unsigned u = m ^ ((m & 0x80000000u) ? 0x80000000u : 0xFFFFFFFFu);
  return __uint_as_float(u);
}
static __device__ __forceinline__ unsigned short f2bf(float x) {
  unsigned u = __float_as_uint(x);
  u += 0x7fffu + ((u >> 16) & 1u);   // round-to-nearest-even
  return (unsigned short)(u >> 16);
}
static __device__ __forceinline__ unsigned pk2(float a, float b) {
  return (unsigned)f2bf(a) | ((unsigned)f2bf(b) << 16);
}

// ---------- CSR build ----------
__global__ void hist_k(const int* __restrict__ dst, int* __restrict__ cnt) {
  int e = blockIdx.x * 256 + threadIdx.x;
  if (e < N_EDGES) atomicAdd(&cnt[dst[e]], 1);
}

__global__ void dinv_k(const int* __restrict__ cnt, float* __restrict__ dinv) {
  int i = blockIdx.x * 256 + threadIdx.x;
  if (i < N_NODES) dinv[i] = rsqrtf((float)cnt[i] + 1.0f);
}

__global__ void scan_block_k(const int* __restrict__ cnt, int* __restrict__ rs,
                             int* __restrict__ bsum) {
  __shared__ int s[256];
  int t = threadIdx.x, i = blockIdx.x * 256 + t;
  int v = (i < N_NODES) ? cnt[i] : 0;
  s[t] = v; __syncthreads();
  for (int off = 1; off < 256; off <<= 1) {
    int a = (t >= off) ? s[t - off] : 0;
    __syncthreads();
    s[t] += a;
    __syncthreads();
  }
  if (i < N_NODES) rs[i] = s[t] - v;       // exclusive
  if (t == 255) bsum[blockIdx.x] = s[255]; // block total
}

__global__ void scan_bsum_k(int* __restrict__ bsum, int nb) {
  __shared__ int s[512];
  int t = threadIdx.x;
  int v = (t < nb) ? bsum[t] : 0;
  s[t] = v; __syncthreads();
  for (int off = 1; off < 512; off <<= 1) {
    int a = (t >= off) ? s[t - off] : 0;
    __syncthreads();
    s[t] += a;
    __syncthreads();
  }
  if (t < nb) bsum[t] = s[t] - v;          // exclusive
}

__global__ void scan_add_k(int* __restrict__ rs, int* __restrict__ cursor,
                           const int* __restrict__ bsum) {
  int i = blockIdx.x * 256 + threadIdx.x;
  if (i < N_NODES) {
    int r = rs[i] + bsum[i >> 8];
    rs[i] = r;
    cursor[i] = r;
  }
}

__global__ void build_k(const int* __restrict__ src, const int* __restrict__ dst,
                        int* __restrict__ cursor, int* __restrict__ srcs) {
  int e = blockIdx.x * 256 + threadIdx.x;
  if (e < N_EDGES) {
    int d = dst[e];
    int p = atomicAdd(&cursor[d], 1);
    srcs[p] = src[e];
  }
}

__global__ void graph_starts_k(const int* __restrict__ batch, int* __restrict__ gstart) {
  int g = threadIdx.x;
  if (g > NGRAPH) return;
  if (g == NGRAPH) { gstart[NGRAPH] = N_NODES; return; }
  int lo = 0, hi = N_NODES;
  while (lo < hi) {
    int mid = (lo + hi) >> 1;
    if (batch[mid] < g) lo = mid + 1; else hi = mid;
  }
  gstart[g] = lo;
}

// ---------- MFMA bf16 GEMM: C = epilogue(A[M,K] @ B[K,F]) ----------
// BM=128, BN=64, BK=32; 256 threads = 4 waves, each wave 32x64.
// f32 inputs converted to bf16 (RNE) during LDS staging; f32 accumulate.
#define LDA 40
#define LDB 40
__global__ __launch_bounds__(256)
void gemm_mfma_k(const float* __restrict__ A, const float* __restrict__ B,
                 const float* __restrict__ bias, const float* __restrict__ add1,
                 const float* __restrict__ add2, float* __restrict__ C,
                 int M, int K, int F, int relu) {
  __shared__ unsigned short As[128 * LDA];
  __shared__ unsigned short Bs[64 * LDB];
  const int tid = threadIdx.x;
  const int wave = tid >> 6;
  const int lane = tid & 63;
  const int quad = lane >> 4;
  const int l16 = lane & 15;
  const int row0 = blockIdx.x * 128;
  const int col0 = blockIdx.y * 64;

  f32x4 acc[2][4];
#pragma unroll
  for (int i = 0; i < 2; i++)
#pragma unroll
    for (int j = 0; j < 4; j++) acc[i][j] = (f32x4){0.f, 0.f, 0.f, 0.f};

  // staging indices
  const int ar = tid >> 1;            // A row within tile, 0..127
  const int ah = (tid & 1) * 16;      // k half: 0 or 16
  const int bn = tid & 63;            // B col within tile
  const int bk = (tid >> 6) * 8;      // k group: 0,8,16,24

  for (int k0 = 0; k0 < K; k0 += 32) {
    if (k0) __syncthreads();
    // stage A tile (128 x 32) as bf16
    {
      int row = row0 + ar;
      uint4 w0, w1;
      if (row < M) {
        const float* ap = A + (size_t)row * K + k0 + ah;
        float4 v0 = *(const float4*)(ap + 0);
        float4 v1 = *(const float4*)(ap + 4);
        float4 v2 = *(const float4*)(ap + 8);
        float4 v3 = *(const float4*)(ap + 12);
        w0.x = pk2(v0.x, v0.y); w0.y = pk2(v0.z, v0.w);
        w0.z = pk2(v1.x, v1.y); w0.w = pk2(v1.z, v1.w);
        w1.x = pk2(v2.x, v2.y); w1.y = pk2(v2.z, v2.w);
        w1.z = pk2(v3.x, v3.y); w1.w = pk2(v3.z, v3.w);
      } else {
        w0 = make_uint4(0, 0, 0, 0); w1 = w0;
      }
      *(uint4*)&As[ar * LDA + ah] = w0;
      *(uint4*)&As[ar * LDA + ah + 8] = w1;
    }
    // stage B tile (32 x 64) transposed -> Bs[n][k]
    {
      const float* bp = B + (size_t)(k0 + bk) * F + col0 + bn;
      float b0 = bp[0 * F], b1 = bp[1 * F], b2 = bp[2 * F], b3 = bp[3 * F];
      float b4 = bp[4 * F], b5 = bp[5 * F], b6 = bp[6 * F], b7 = bp[7 * F];
      uint4 w;
      w.x = pk2(b0, b1); w.y = pk2(b2, b3); w.z = pk2(b4, b5); w.w = pk2(b6, b7);
      *(uint4*)&Bs[bn * LDB + bk] = w;
    }
    __syncthreads();

    bf16x8 af[2], bf[4];
#pragma unroll
    for (int mt = 0; mt < 2; mt++) {
      int m = wave * 32 + mt * 16 + l16;
      af[mt] = *(bf16x8*)&As[m * LDA + quad * 8];
    }
#pragma unroll
    for (int nt = 0; nt < 4; nt++) {
      int n = nt * 16 + l16;
      bf[nt] = *(bf16x8*)&Bs[n * LDB + quad * 8];
    }
#pragma unroll
    for (int mt = 0; mt < 2; mt++)
#pragma unroll
      for (int nt = 0; nt < 4; nt++)
        acc[mt][nt] = __builtin_amdgcn_mfma_f32_16x16x32_bf16(af[mt], bf[nt], acc[mt][nt], 0, 0, 0);
  }

  // epilogue: D col = lane&15 (+16*nt), row = quad*4+reg (+ wave*32 + mt*16)
#pragma unroll
  for (int mt = 0; mt < 2; mt++) {
#pragma unroll
    for (int r = 0; r < 4; r++) {
      int row = row0 + wave * 32 + mt * 16 + quad * 4 + r;
      if (row >= M) continue;
#pragma unroll
      for (int nt = 0; nt < 4; nt++) {
        int col = col0 + nt * 16 + l16;
        float v = acc[mt][nt][r];
        if (bias) v += bias[col];
        if (relu) v = fmaxf(v, 0.f);
        size_t off = (size_t)row * F + col;
        if (add1) v += add1[off];
        if (add2) v += add2[off];
        C[off] = v;
      }
    }
  }
}

// ---------- small f32 GEMM (kept for the tiny 64x192x192 zg GEMM) ----------
__global__ __launch_bounds__(256)
void gemm_kernel(const float* __restrict__ A, const float* __restrict__ B,
                 const float* __restrict__ bias, const float* __restrict__ add1,
                 const float* __restrict__ add2, float* __restrict__ C,
                 int M, int K, int F, int relu) {
  __shared__ float Asm[16][65];
  __shared__ float Bsm[16][65];
  const int tid = threadIdx.x;
  const int tx = tid & 15, ty = tid >> 4;
  const int row0 = blockIdx.x * 64;
  const int col0 = blockIdx.y * 64;
  float acc[4][4];
#pragma unroll
  for (int i = 0; i < 4; i++)
#pragma unroll
    for (int j = 0; j < 4; j++) acc[i][j] = 0.f;

  for (int k0 = 0; k0 < K; k0 += 16) {
#pragma unroll
    for (int l = 0; l < 4; l++) {
      int idx = tid + l * 256;
      int m = idx >> 4, k = idx & 15;
      int r = row0 + m;
      Asm[k][m] = (r < M) ? A[(size_t)r * K + k0 + k] : 0.f;
    }
#pragma unroll
    for (int l = 0; l < 4; l++) {
      int idx = tid + l * 256;
      int k = idx >> 6, n = idx & 63;
      Bsm[k][n] = B[(size_t)(k0 + k) * F + col0 + n];
    }
    __syncthreads();
#pragma unroll
    for (int k = 0; k < 16; k++) {
      float a[4], b[4];
#pragma unroll
      for (int i = 0; i < 4; i++) a[i] = Asm[k][ty * 4 + i];
#pragma unroll
      for (int j = 0; j < 4; j++) b[j] = Bsm[k][tx * 4 + j];
#pragma unroll
      for (int i = 0; i < 4; i++)
#pragma unroll
        for (int j = 0; j < 4; j++) acc[i][j] += a[i] * b[j];
    }
    __syncthreads();
  }
#pragma unroll
  for (int i = 0; i < 4; i++) {
    int r = row0 + ty * 4 + i;
    if (r >= M) continue;
#pragma unroll
    for (int j = 0; j < 4; j++) {
      int c = col0 + tx * 4 + j;
      float v = acc[i][j];
      if (bias) v += bias[c];
      if (relu) v = fmaxf(v, 0.f);
      size_t off = (size_t)r * F + c;
      if (add1) v += add1[off];
      if (add2) v += add2[off];
      C[off] = v;
    }
  }
}

// ---------- elementwise: out = a + pe3 (pe tiled 3x over 192) ----------
__global__ void add_pe3_k(const float* __restrict__ a, const float* __restrict__ pe,
                          float* __restrict__ out) {
  int t = blockIdx.x * 256 + threadIdx.x;
  if (t >= N_NODES * 48) return;
  int i = t / 48, c = (t - i * 48) * 4;
  float4 v = *(const float4*)(a + (size_t)i * 192 + c);
  float4 p = *(const float4*)(pe + (size_t)i * 64 + (c & 63));
  v.x += p.x; v.y += p.y; v.z += p.z; v.w += p.w;
  *(float4*)(out + (size_t)i * 192 + c) = v;
}

// ---------- aggregations over CSR (gather form, no float atomics) ----------
template <int F>
__global__ void agg_mpnn_k(const float* __restrict__ x, const int* __restrict__ rowstart,
                           const int* __restrict__ cnt, const int* __restrict__ srcs,
                           float* __restrict__ out) {
  constexpr int F4 = F / 4;
  int t = blockIdx.x * 256 + threadIdx.x;
  if (t >= N_NODES * F4) return;
  int i = t / F4, c = (t - i * F4) * 4;
  float4 acc = make_float4(0.f, 0.f, 0.f, 0.f);
  int e = rowstart[i], e1 = e + cnt[i];
  for (; e < e1; ++e) {
    int s = srcs[e];
    float4 v = *(const float4*)(x + (size_t)s * F + c);
    acc.x += v.x; acc.y += v.y; acc.z += v.z; acc.w += v.w;
  }
  *(float4*)(out + (size_t)i * F + c) = acc;
}

template <int F, bool RELU, bool HAS_BIAS>
__global__ void agg_gcn_k(const float* __restrict__ x, const int* __restrict__ rowstart,
                          const int* __restrict__ cnt, const int* __restrict__ srcs,
                          const float* __restrict__ dinv, const float* __restrict__ bias,
                          float* __restrict__ out) {
  constexpr int F4 = F / 4;
  int t = blockIdx.x * 256 + threadIdx.x;
  if (t >= N_NODES * F4) return;
  int i = t / F4, c = (t - i * F4) * 4;
  float4 acc = make_float4(0.f, 0.f, 0.f, 0.f);
  int e = rowstart[i], e1 = e + cnt[i];
  for (; e < e1; ++e) {
    int s = srcs[e];
    float w = dinv[s];
    float4 v = *(const float4*)(x + (size_t)s * F + c);
    acc.x += w * v.x; acc.y += w * v.y; acc.z += w * v.z; acc.w += w * v.w;
  }
  float di = dinv[i];
  float sw = di * di;
  float4 self = *(const float4*)(x + (size_t)i * F + c);
  float4 r;
  r.x = di * acc.x + sw * self.x;
  r.y = di * acc.y + sw * self.y;
  r.z = di * acc.z + sw * self.z;
  r.w = di * acc.w + sw * self.w;
  if (HAS_BIAS) {
    float4 b = *(const float4*)(bias + c);
    r.x += b.x; r.y += b.y; r.z += b.z; r.w += b.w;
  }
  if (RELU) {
    r.x = fmaxf(r.x, 0.f); r.y = fmaxf(r.y, 0.f);
    r.z = fmaxf(r.z, 0.f); r.w = fmaxf(r.w, 0.f);
  }
  *(float4*)(out + (size_t)i * F + c) = r;
}

// decoder GCN: x-rows come from 64-row table zgW via batch lookup
__global__ void agg_gcn_dec_k(const float* __restrict__ zgW, const int* __restrict__ rowstart,
                              const int* __restrict__ cnt, const int* __restrict__ srcs,
                              const int* __restrict__ batch, const float* __restrict__ dinv,
                              const float* __restrict__ bias, float* __restrict__ out) {
  int t = blockIdx.x * 256 + threadIdx.x;
  if (t >= N_NODES * 48) return;
  int i = t / 48, c = (t - i * 48) * 4;
  float4 acc = make_float4(0.f, 0.f, 0.f, 0.f);
  int e = rowstart[i], e1 = e + cnt[i];
  for (; e < e1; ++e) {
    int s = srcs[e];
    float w = dinv[s];
    float4 v = *(const float4*)(zgW + (size_t)batch[s] * 192 + c);
    acc.x += w * v.x; acc.y += w * v.y; acc.z += w * v.z; acc.w += w * v.w;
  }
  float di = dinv[i];
  float sw = di * di;
  float4 self = *(const float4*)(zgW + (size_t)batch[i] * 192 + c);
  float4 b = *(const float4*)(bias + c);
  float4 r;
  r.x = fmaxf(di * acc.x + sw * self.x + b.x, 0.f);
  r.y = fmaxf(di * acc.y + sw * self.y + b.y, 0.f);
  r.z = fmaxf(di * acc.z + sw * self.z + b.z, 0.f);
  r.w = fmaxf(di * acc.w + sw * self.w + b.w, 0.f);
  *(float4*)(out + (size_t)i * 192 + c) = r;
}

// ---------- segment softmax (per graph, per channel) ----------
__global__ void init_gmax_k(unsigned* __restrict__ gmaxu) {
  int t = blockIdx.x * 256 + threadIdx.x;
  if (t < NGRAPH * 192) gmaxu[t] = 0x007FFFFFu; // flip(-inf)
}

__global__ void seg_max_k(const float* __restrict__ gate, const int* __restrict__ gstart,
                          unsigned* __restrict__ gmaxu) {
  int g = blockIdx.x, f = threadIdx.x;
  int lo = gstart[g], hi = gstart[g + 1];
  int len = hi - lo;
  if (len <= 0) return;
  int per = (len + gridDim.y - 1) / gridDim.y;
  int a = lo + blockIdx.y * per;
  int b = min(a + per, hi);
  if (a >= b) return;
  float m = -INFINITY;
  for (int i = a; i < b; i++) m = fmaxf(m, gate[(size_t)i * 192 + f]);
  atomicMax(&gmaxu[g * 192 + f], flip_f(m));
}

__global__ void seg_sum_k(const float* __restrict__ gate, const float* __restrict__ z,
                          const int* __restrict__ gstart, const unsigned* __restrict__ gmaxu,
                          float* __restrict__ esum, float* __restrict__ znum) {
  int g = blockIdx.x, f = threadIdx.x;
  int lo = gstart[g], hi = gstart[g + 1];
  int len = hi - lo;
  if (len <= 0) return;
  int per = (len + gridDim.y - 1) / gridDim.y;
  int a = lo + blockIdx.y * per;
  int b = min(a + per, hi);
  if (a >= b) return;
  float gm = unflip_f(gmaxu[g * 192 + f]);
  float se = 0.f, sz = 0.f;
  for (int i = a; i < b; i++) {
    float e = expf(gate[(size_t)i * 192 + f] - gm);
    se += e;
    sz += e * z[(size_t)i * 192 + f];
  }
  atomicAdd(&esum[g * 192 + f], se);
  atomicAdd(&znum[g * 192 + f], sz);
}

__global__ void zg_fin_k(const float* __restrict__ znum, const float* __restrict__ esum,
                         float* __restrict__ zg) {
  int t = blockIdx.x * 256 + threadIdx.x;
  if (t >= NGRAPH * 192) return;
  float es = esum[t];
  zg[t] = (es > 0.f) ? znum[t] / es : 0.f;
}

// ---------- launch ----------
extern "C" void kernel_launch(void* const* d_in, const int* in_sizes, int n_in,
                              void* d_out, int out_size, void* d_ws, size_t ws_size,
                              hipStream_t stream) {
  const float* x1 = (const float*)d_in[0];
  const float* x2 = (const float*)d_in[1];
  const float* pe = (const float*)d_in[2];
  const int* ei = (const int*)d_in[3];
  const int* src = ei;
  const int* dst = ei + N_EDGES;
  const int* batch = (const int*)d_in[4];
  const float* Wc  = (const float*)d_in[5];  const float* bc  = (const float*)d_in[6];
  const float* Wmf = (const float*)d_in[7];  const float* bmf = (const float*)d_in[8];
  const float* Wgf = (const float*)d_in[9];  const float* bgf = (const float*)d_in[10];
  const float* Wmc = (const float*)d_in[11]; const float* bmc = (const float*)d_in[12];
  const float* Wgc = (const float*)d_in[13]; const float* bgc = (const float*)d_in[14];
  const float* Wa1 = (const float*)d_in[15]; const float* ba1 = (const float*)d_in[16];
  const float* Wa2 = (const float*)d_in[17]; const float* ba2 = (const float*)d_in[18];
  const float* Wgd = (const float*)d_in[19]; const float* bgd = (const float*)d_in[20];
  const float* Wd1 = (const float*)d_in[21]; const float* bd1 = (const float*)d_in[22];
  const float* Wd2 = (const float*)d_in[23]; const float* bd2 = (const float*)d_in[24];
  const float* Wd3 = (const float*)d_in[25]; const float* bd3 = (const float*)d_in[26];
  float* out = (float*)d_out;

  float* W = (float*)d_ws;
  size_t o = 0;
  float* P0  = W + o; o += (size_t)N_NODES * 192; // x1_res -> z (in place)
  float* P1  = W + o; o += (size_t)N_NODES * 256; // h0 -> h1 -> g1 -> t1
  float* P2  = W + o; o += (size_t)N_NODES * 192; // agg1 -> gate -> t0 -> agg_b -> agg_c
  float* P5a = W + o; o += (size_t)N_NODES * 32;  // aggc
  float* P5b = W + o; o += (size_t)N_NODES * 64;  // c1
  float* P5c = W + o; o += (size_t)N_NODES * 64;  // cagg
  float* dinv = W + o; o += N_NODES;
  unsigned* gmaxu = (unsigned*)(W + o); o += NGRAPH * 192;
  float* esum = W + o; o += NGRAPH * 192;
  float* znum = W + o; o += NGRAPH * 192;
  float* zg   = W + o; o += NGRAPH * 192;
  float* zgW  = W + o; o += NGRAPH * 192;
  int* cnt      = (int*)(W + o); o += N_NODES;
  int* rowstart = (int*)(W + o); o += N_NODES;
  int* cursor   = (int*)(W + o); o += N_NODES;
  int* srcs     = (int*)(W + o); o += N_EDGES;
  int* bsum     = (int*)(W + o); o += 512;
  int* gstart   = (int*)(W + o); o += 80;

  float* P3 = out;                           // d_out lower half: hW -> agg_a -> t2
  float* P4 = out + (size_t)N_NODES * 192;   // d_out upper half: h2 -> z1_res

  const int TB = 256;
  hipMemsetAsync(cnt, 0, N_NODES * sizeof(int), stream);
  hipMemsetAsync(esum, 0, 2 * NGRAPH * 192 * sizeof(float), stream);

  // CSR build (dst-sorted)
  hist_k<<<(N_EDGES + TB - 1) / TB, TB, 0, stream>>>(dst, cnt);
  dinv_k<<<(N_NODES + TB - 1) / TB, TB, 0, stream>>>(cnt, dinv);
  int nb = (N_NODES + 255) / 256;
  scan_block_k<<<nb, 256, 0, stream>>>(cnt, rowstart, bsum);
  scan_bsum_k<<<1, 512, 0, stream>>>(bsum, nb);
  scan_add_k<<<nb, 256, 0, stream>>>(rowstart, cursor, bsum);
  build_k<<<(N_EDGES + TB - 1) / TB, TB, 0, stream>>>(src, dst, cursor, srcs);
  graph_starts_k<<<1, 128, 0, stream>>>(batch, gstart);

  int mb = (N_NODES + 127) / 128;
  dim3 g192(mb, 3);
  dim3 g256(mb, 4);
  dim3 g384(mb, 6);
  dim3 g64n(mb, 1);
  int ew192 = (N_NODES * 48 + TB - 1) / TB;

  // ---- encoder ----
  gemm_mfma_k<<<g192, 256, 0, stream>>>(x1, Wc, bc, nullptr, nullptr, P0, N_NODES, 384, 192, 1);
  add_pe3_k<<<ew192, TB, 0, stream>>>(P0, pe, P1);
  agg_mpnn_k<192><<<ew192, TB, 0, stream>>>(P1, rowstart, cnt, srcs, P2);
  gemm_mfma_k<<<g256, 256, 0, stream>>>(P2, Wmf, bmf, nullptr, nullptr, P1, N_NODES, 192, 256, 1);
  gemm_mfma_k<<<g192, 256, 0, stream>>>(P1, Wgf, nullptr, nullptr, nullptr, P3, N_NODES, 256, 192, 0);
  agg_gcn_k<192, true, true><<<ew192, TB, 0, stream>>>(P3, rowstart, cnt, srcs, dinv, bgf, P4);
  agg_mpnn_k<32><<<(N_NODES * 8 + TB - 1) / TB, TB, 0, stream>>>(x2, rowstart, cnt, srcs, P5a);
  gemm_mfma_k<<<g64n, 256, 0, stream>>>(P5a, Wmc, bmc, nullptr, nullptr, P5b, N_NODES, 32, 64, 1);
  agg_gcn_k<64, false, false><<<(N_NODES * 16 + TB - 1) / TB, TB, 0, stream>>>(P5b, rowstart, cnt, srcs, dinv, nullptr, P5c);
  // z = relu(cagg@Wgc + bgc) + h2 + x1_res  (in place over x1_res)
  gemm_mfma_k<<<g192, 256, 0, stream>>>(P5c, Wgc, bgc, P4, P0, P0, N_NODES, 64, 192, 1);

  // ---- attention aggregation ----
  gemm_mfma_k<<<g256, 256, 0, stream>>>(P0, Wa1, ba1, nullptr, nullptr, P1, N_NODES, 192, 256, 1);
  gemm_mfma_k<<<g192, 256, 0, stream>>>(P1, Wa2, ba2, nullptr, nullptr, P2, N_NODES, 256, 192, 0);
  init_gmax_k<<<(NGRAPH * 192 + TB - 1) / TB, TB, 0, stream>>>(gmaxu);
  dim3 sg(NGRAPH, 16);
  seg_max_k<<<sg, 192, 0, stream>>>(P2, gstart, gmaxu);
  seg_sum_k<<<sg, 192, 0, stream>>>(P2, P0, gstart, gmaxu, esum, znum);
  zg_fin_k<<<(NGRAPH * 192 + TB - 1) / TB, TB, 0, stream>>>(znum, esum, zg);
  dim3 gz(1, 3);
  gemm_kernel<<<gz, 256, 0, stream>>>(zg, Wgd, nullptr, nullptr, nullptr, zgW, NGRAPH, 192, 192, 0);

  // ---- decoder ----
  agg_gcn_dec_k<<<ew192, TB, 0, stream>>>(zgW, rowstart, cnt, srcs, batch, dinv, bgd, P4);
  add_pe3_k<<<ew192, TB, 0, stream>>>(P4, pe, P2);                       // t0
  agg_mpnn_k<192><<<ew192, TB, 0, stream>>>(P2, rowstart, cnt, srcs, P3); // agg_a
  gemm_mfma_k<<<g192, 256, 0, stream>>>(P3, Wd1, bd1, nullptr, nullptr, P1, N_NODES, 192, 192, 1); // t1
  agg_mpnn_k<192><<<ew192, TB, 0, stream>>>(P1, rowstart, cnt, srcs, P2); // agg_b
  gemm_mfma_k<<<g192, 256, 0, stream>>>(P2, Wd2, bd2, P4, nullptr, P3, N_NODES, 192, 192, 1); // t2 = relu+z1_res
  agg_mpnn_k<192><<<ew192, TB, 0, stream>>>(P3, rowstart, cnt, srcs, P2); // agg_c
  gemm_mfma_k<<<g384, 256, 0, stream>>>(P2, Wd3, bd3, nullptr, nullptr, out, N_NODES, 192, 384, 1);
  (void)in_sizes; (void)n_in; (void)out_size; (void)ws_size;
}

// Round 3
// 1651.280 us; speedup vs baseline: 1.8505x; 1.1575x over previous
//
#include <hip/hip_runtime.h>
#include <math.h>

#define N_NODES 100000
#define N_EDGES 800000
#define NGRAPH  64

typedef __attribute__((ext_vector_type(8))) __bf16 bf16x8;
typedef __attribute__((ext_vector_type(4))) float f32x4;

// ---------- helpers ----------
static __device__ __forceinline__ unsigned flip_f(float x) {
  unsigned u = __float_as_uint(x);
  return u ^ ((u & 0x80000000u) ? 0xFFFFFFFFu : 0x80000000u);
}
static __device__ __forceinline__ float unflip_f(unsigned m) {
  unsigned u = m ^ ((m & 0x80000000u) ? 0x80000000u : 0xFFFFFFFFu);
  return __uint_as_float(u);
}
static __device__ __forceinline__ unsigned short f2bf(float x) {
  unsigned u = __float_as_uint(x);
  u += 0x7fffu + ((u >> 16) & 1u);   // RNE
  return (unsigned short)(u >> 16);
}
static __device__ __forceinline__ unsigned pk2(float a, float b) {
  return (unsigned)f2bf(a) | ((unsigned)f2bf(b) << 16);
}
static __device__ __forceinline__ float bf2f(unsigned short h) {
  return __uint_as_float((unsigned)h << 16);
}
static __device__ __forceinline__ void unpack8(uint4 w, float* f) {
  f[0] = __uint_as_float(w.x << 16); f[1] = __uint_as_float(w.x & 0xFFFF0000u);
  f[2] = __uint_as_float(w.y << 16); f[3] = __uint_as_float(w.y & 0xFFFF0000u);
  f[4] = __uint_as_float(w.z << 16); f[5] = __uint_as_float(w.z & 0xFFFF0000u);
  f[6] = __uint_as_float(w.w << 16); f[7] = __uint_as_float(w.w & 0xFFFF0000u);
}
static __device__ __forceinline__ uint4 pack8(const float* f) {
  uint4 w;
  w.x = pk2(f[0], f[1]); w.y = pk2(f[2], f[3]);
  w.z = pk2(f[4], f[5]); w.w = pk2(f[6], f[7]);
  return w;
}

// ---------- CSR build ----------
__global__ void hist_k(const int* __restrict__ dst, int* __restrict__ cnt) {
  int e = blockIdx.x * 256 + threadIdx.x;
  if (e < N_EDGES) atomicAdd(&cnt[dst[e]], 1);
}

__global__ void dinv_k(const int* __restrict__ cnt, float* __restrict__ dinv) {
  int i = blockIdx.x * 256 + threadIdx.x;
  if (i < N_NODES) dinv[i] = rsqrtf((float)cnt[i] + 1.0f);
}

__global__ void scan_block_k(const int* __restrict__ cnt, int* __restrict__ rs,
                             int* __restrict__ bsum) {
  __shared__ int s[256];
  int t = threadIdx.x, i = blockIdx.x * 256 + t;
  int v = (i < N_NODES) ? cnt[i] : 0;
  s[t] = v; __syncthreads();
  for (int off = 1; off < 256; off <<= 1) {
    int a = (t >= off) ? s[t - off] : 0;
    __syncthreads();
    s[t] += a;
    __syncthreads();
  }
  if (i < N_NODES) rs[i] = s[t] - v;
  if (t == 255) bsum[blockIdx.x] = s[255];
}

__global__ void scan_bsum_k(int* __restrict__ bsum, int nb) {
  __shared__ int s[512];
  int t = threadIdx.x;
  int v = (t < nb) ? bsum[t] : 0;
  s[t] = v; __syncthreads();
  for (int off = 1; off < 512; off <<= 1) {
    int a = (t >= off) ? s[t - off] : 0;
    __syncthreads();
    s[t] += a;
    __syncthreads();
  }
  if (t < nb) bsum[t] = s[t] - v;
}

__global__ void scan_add_k(int* __restrict__ rs, int* __restrict__ cursor,
                           const int* __restrict__ bsum) {
  int i = blockIdx.x * 256 + threadIdx.x;
  if (i < N_NODES) {
    int r = rs[i] + bsum[i >> 8];
    rs[i] = r;
    cursor[i] = r;
  }
}

__global__ void build_k(const int* __restrict__ src, const int* __restrict__ dst,
                        int* __restrict__ cursor, int* __restrict__ srcs) {
  int e = blockIdx.x * 256 + threadIdx.x;
  if (e < N_EDGES) {
    int d = dst[e];
    int p = atomicAdd(&cursor[d], 1);
    srcs[p] = src[e];
  }
}

__global__ void graph_starts_k(const int* __restrict__ batch, int* __restrict__ gstart) {
  int g = threadIdx.x;
  if (g > NGRAPH) return;
  if (g == NGRAPH) { gstart[NGRAPH] = N_NODES; return; }
  int lo = 0, hi = N_NODES;
  while (lo < hi) {
    int mid = (lo + hi) >> 1;
    if (batch[mid] < g) lo = mid + 1; else hi = mid;
  }
  gstart[g] = lo;
}

// ---------- templated MFMA bf16 GEMM, single pass over full F ----------
// BM=64*MT, BN=16*NT; 4 waves, wave handles MT*16 rows x BN cols.
// AT=float (convert in staging) or ushort (bf16 pass-through).
// add1/add2 are bf16; output bf16 or f32.
template <typename AT, int MT, int NT, bool OUT_F32>
__global__ __launch_bounds__(256)
void gemm_t(const AT* __restrict__ A, const float* __restrict__ B,
            const float* __restrict__ bias,
            const unsigned short* __restrict__ add1,
            const unsigned short* __restrict__ add2,
            void* __restrict__ Cv, int M, int K, int F, int relu) {
  constexpr int BM = 64 * MT;
  constexpr int BN = 16 * NT;
  __shared__ unsigned short As[BM * 40];
  __shared__ unsigned short Bs[BN * 40];
  const int tid = threadIdx.x;
  const int wave = tid >> 6, lane = tid & 63;
  const int quad = lane >> 4, l16 = lane & 15;
  const int row0 = blockIdx.x * BM;
  const int col0 = blockIdx.y * BN;

  f32x4 acc[MT][NT];
#pragma unroll
  for (int i = 0; i < MT; i++)
#pragma unroll
    for (int j = 0; j < NT; j++) acc[i][j] = (f32x4){0.f, 0.f, 0.f, 0.f};

  for (int k0 = 0; k0 < K; k0 += 32) {
    if (k0) __syncthreads();
    // ---- stage A (BM x 32) ----
    if constexpr (sizeof(AT) == 4) {
      // f32 -> bf16 conversion path (MT==2 only in practice)
      int ar = tid >> 1, ah = (tid & 1) * 16;
      int row = row0 + ar;
      uint4 w0 = make_uint4(0, 0, 0, 0), w1 = w0;
      if (row < M) {
        const float* ap = (const float*)A + (size_t)row * K + k0 + ah;
        float4 v0 = *(const float4*)(ap + 0);
        float4 v1 = *(const float4*)(ap + 4);
        float4 v2 = *(const float4*)(ap + 8);
        float4 v3 = *(const float4*)(ap + 12);
        w0.x = pk2(v0.x, v0.y); w0.y = pk2(v0.z, v0.w);
        w0.z = pk2(v1.x, v1.y); w0.w = pk2(v1.z, v1.w);
        w1.x = pk2(v2.x, v2.y); w1.y = pk2(v2.z, v2.w);
        w1.z = pk2(v3.x, v3.y); w1.w = pk2(v3.z, v3.w);
      }
      *(uint4*)&As[ar * 40 + ah] = w0;
      *(uint4*)&As[ar * 40 + ah + 8] = w1;
    } else if constexpr (MT == 2) {
      int ar = tid >> 1, ah = (tid & 1) * 16;
      int row = row0 + ar;
      uint4 w0 = make_uint4(0, 0, 0, 0), w1 = w0;
      if (row < M) {
        const unsigned short* ap = (const unsigned short*)A + (size_t)row * K + k0 + ah;
        w0 = *(const uint4*)ap;
        w1 = *(const uint4*)(ap + 8);
      }
      *(uint4*)&As[ar * 40 + ah] = w0;
      *(uint4*)&As[ar * 40 + ah + 8] = w1;
    } else {
      int ar = tid >> 2, ap4 = (tid & 3) * 8;
      int row = row0 + ar;
      uint4 w = make_uint4(0, 0, 0, 0);
      if (row < M)
        w = *(const uint4*)((const unsigned short*)A + (size_t)row * K + k0 + ap4);
      *(uint4*)&As[ar * 40 + ap4] = w;
    }
    // ---- stage B (32 x BN) transposed, f32 -> bf16 ----
#pragma unroll
    for (int c = 0; c < NT / 4; c++) {
      int bn = tid & 63, bkk = (tid >> 6) * 8;
      int col = col0 + c * 64 + bn;
      const float* bp = B + (size_t)(k0 + bkk) * F + col;
      uint4 w;
      w.x = pk2(bp[0 * F], bp[1 * F]); w.y = pk2(bp[2 * F], bp[3 * F]);
      w.z = pk2(bp[4 * F], bp[5 * F]); w.w = pk2(bp[6 * F], bp[7 * F]);
      *(uint4*)&Bs[(c * 64 + bn) * 40 + bkk] = w;
    }
    __syncthreads();

    bf16x8 af[MT], bfr[NT];
#pragma unroll
    for (int mt = 0; mt < MT; mt++) {
      int m = wave * (MT * 16) + mt * 16 + l16;
      af[mt] = *(bf16x8*)&As[m * 40 + quad * 8];
    }
#pragma unroll
    for (int nt = 0; nt < NT; nt++) {
      int n = nt * 16 + l16;
      bfr[nt] = *(bf16x8*)&Bs[n * 40 + quad * 8];
    }
#pragma unroll
    for (int mt = 0; mt < MT; mt++)
#pragma unroll
      for (int nt = 0; nt < NT; nt++)
        acc[mt][nt] = __builtin_amdgcn_mfma_f32_16x16x32_bf16(af[mt], bfr[nt], acc[mt][nt], 0, 0, 0);
  }

  float* Cf = (float*)Cv;
  unsigned short* Ch = (unsigned short*)Cv;
#pragma unroll
  for (int mt = 0; mt < MT; mt++) {
#pragma unroll
    for (int r = 0; r < 4; r++) {
      int row = row0 + wave * (MT * 16) + mt * 16 + quad * 4 + r;
      if (row >= M) continue;
#pragma unroll
      for (int nt = 0; nt < NT; nt++) {
        int col = col0 + nt * 16 + l16;
        float v = acc[mt][nt][r];
        if (bias) v += bias[col];
        if (relu) v = fmaxf(v, 0.f);
        size_t off = (size_t)row * F + col;
        if (add1) v += bf2f(add1[off]);
        if (add2) v += bf2f(add2[off]);
        if (OUT_F32) Cf[off] = v; else Ch[off] = f2bf(v);
      }
    }
  }
}

// ---------- small f32 GEMM (64x192x192 zg GEMM only) ----------
__global__ __launch_bounds__(256)
void gemm_kernel(const float* __restrict__ A, const float* __restrict__ B,
                 const float* __restrict__ bias, float* __restrict__ C,
                 int M, int K, int F) {
  __shared__ float Asm[16][65];
  __shared__ float Bsm[16][65];
  const int tid = threadIdx.x;
  const int tx = tid & 15, ty = tid >> 4;
  const int row0 = blockIdx.x * 64;
  const int col0 = blockIdx.y * 64;
  float acc[4][4];
#pragma unroll
  for (int i = 0; i < 4; i++)
#pragma unroll
    for (int j = 0; j < 4; j++) acc[i][j] = 0.f;

  for (int k0 = 0; k0 < K; k0 += 16) {
#pragma unroll
    for (int l = 0; l < 4; l++) {
      int idx = tid + l * 256;
      int m = idx >> 4, k = idx & 15;
      int r = row0 + m;
      Asm[k][m] = (r < M) ? A[(size_t)r * K + k0 + k] : 0.f;
    }
#pragma unroll
    for (int l = 0; l < 4; l++) {
      int idx = tid + l * 256;
      int k = idx >> 6, n = idx & 63;
      Bsm[k][n] = B[(size_t)(k0 + k) * F + col0 + n];
    }
    __syncthreads();
#pragma unroll
    for (int k = 0; k < 16; k++) {
      float a[4], b[4];
#pragma unroll
      for (int i = 0; i < 4; i++) a[i] = Asm[k][ty * 4 + i];
#pragma unroll
      for (int j = 0; j < 4; j++) b[j] = Bsm[k][tx * 4 + j];
#pragma unroll
      for (int i = 0; i < 4; i++)
#pragma unroll
        for (int j = 0; j < 4; j++) acc[i][j] += a[i] * b[j];
    }
    __syncthreads();
  }
#pragma unroll
  for (int i = 0; i < 4; i++) {
    int r = row0 + ty * 4 + i;
    if (r >= M) continue;
#pragma unroll
    for (int j = 0; j < 4; j++) {
      int c = col0 + tx * 4 + j;
      float v = acc[i][j];
      if (bias) v += bias[c];
      C[(size_t)r * F + c] = v;
    }
  }
}

// ---------- elementwise: out = a + pe3 (bf16 + f32 -> bf16) ----------
__global__ void add_pe3_bf(const unsigned short* __restrict__ a, const float* __restrict__ pe,
                           unsigned short* __restrict__ out) {
  int t = blockIdx.x * 256 + threadIdx.x;
  if (t >= N_NODES * 24) return;
  int i = t / 24, c = (t - i * 24) * 8;
  uint4 w = *(const uint4*)(a + (size_t)i * 192 + c);
  float f[8]; unpack8(w, f);
  const float* p = pe + (size_t)i * 64 + (c & 63);
#pragma unroll
  for (int j = 0; j < 8; j++) f[j] += p[j];
  *(uint4*)(out + (size_t)i * 192 + c) = pack8(f);
}

// ---------- aggregations (bf16 in, f32 accumulate, bf16 out) ----------
template <int F>
__global__ void agg_mpnn_bf(const unsigned short* __restrict__ x, const int* __restrict__ rowstart,
                            const int* __restrict__ cnt, const int* __restrict__ srcs,
                            unsigned short* __restrict__ out) {
  constexpr int F8 = F / 8;
  int t = blockIdx.x * 256 + threadIdx.x;
  if (t >= N_NODES * F8) return;
  int i = t / F8, c = (t - i * F8) * 8;
  float a[8] = {0.f, 0.f, 0.f, 0.f, 0.f, 0.f, 0.f, 0.f};
  int e = rowstart[i], e1 = e + cnt[i];
  for (; e < e1; ++e) {
    int s = srcs[e];
    uint4 w = *(const uint4*)(x + (size_t)s * F + c);
    float f[8]; unpack8(w, f);
#pragma unroll
    for (int j = 0; j < 8; j++) a[j] += f[j];
  }
  *(uint4*)(out + (size_t)i * F + c) = pack8(a);
}

template <int F, bool RELU, bool HAS_BIAS>
__global__ void agg_gcn_bf(const unsigned short* __restrict__ x, const int* __restrict__ rowstart,
                           const int* __restrict__ cnt, const int* __restrict__ srcs,
                           const float* __restrict__ dinv, const float* __restrict__ bias,
                           unsigned short* __restrict__ out) {
  constexpr int F8 = F / 8;
  int t = blockIdx.x * 256 + threadIdx.x;
  if (t >= N_NODES * F8) return;
  int i = t / F8, c = (t - i * F8) * 8;
  float a[8] = {0.f, 0.f, 0.f, 0.f, 0.f, 0.f, 0.f, 0.f};
  int e = rowstart[i], e1 = e + cnt[i];
  for (; e < e1; ++e) {
    int s = srcs[e];
    float w = dinv[s];
    uint4 wv = *(const uint4*)(x + (size_t)s * F + c);
    float f[8]; unpack8(wv, f);
#pragma unroll
    for (int j = 0; j < 8; j++) a[j] += w * f[j];
  }
  float di = dinv[i];
  float sw = di * di;
  uint4 sv = *(const uint4*)(x + (size_t)i * F + c);
  float sf[8]; unpack8(sv, sf);
  float r[8];
#pragma unroll
  for (int j = 0; j < 8; j++) {
    float v = di * a[j] + sw * sf[j];
    if (HAS_BIAS) v += bias[c + j];
    if (RELU) v = fmaxf(v, 0.f);
    r[j] = v;
  }
  *(uint4*)(out + (size_t)i * F + c) = pack8(r);
}

// x2 aggregation: f32 input (32 cols), bf16 out
__global__ void agg_x2_k(const float* __restrict__ x, const int* __restrict__ rowstart,
                         const int* __restrict__ cnt, const int* __restrict__ srcs,
                         unsigned short* __restrict__ out) {
  int t = blockIdx.x * 256 + threadIdx.x;
  if (t >= N_NODES * 8) return;
  int i = t >> 3, c = (t & 7) * 4;
  float4 acc = make_float4(0.f, 0.f, 0.f, 0.f);
  int e = rowstart[i], e1 = e + cnt[i];
  for (; e < e1; ++e) {
    int s = srcs[e];
    float4 v = *(const float4*)(x + (size_t)s * 32 + c);
    acc.x += v.x; acc.y += v.y; acc.z += v.z; acc.w += v.w;
  }
  ushort4 o;
  o.x = f2bf(acc.x); o.y = f2bf(acc.y); o.z = f2bf(acc.z); o.w = f2bf(acc.w);
  *(ushort4*)(out + (size_t)i * 32 + c) = o;
}

// decoder GCN: source rows from 64-row f32 table zgW via batch
__global__ void agg_gcn_dec_bf(const float* __restrict__ zgW, const int* __restrict__ rowstart,
                               const int* __restrict__ cnt, const int* __restrict__ srcs,
                               const int* __restrict__ batch, const float* __restrict__ dinv,
                               const float* __restrict__ bias, unsigned short* __restrict__ out) {
  int t = blockIdx.x * 256 + threadIdx.x;
  if (t >= N_NODES * 24) return;
  int i = t / 24, c = (t - i * 24) * 8;
  float a[8] = {0.f, 0.f, 0.f, 0.f, 0.f, 0.f, 0.f, 0.f};
  int e = rowstart[i], e1 = e + cnt[i];
  for (; e < e1; ++e) {
    int s = srcs[e];
    float w = dinv[s];
    const float* v = zgW + (size_t)batch[s] * 192 + c;
#pragma unroll
    for (int j = 0; j < 8; j++) a[j] += w * v[j];
  }
  float di = dinv[i];
  float sw = di * di;
  const float* sv = zgW + (size_t)batch[i] * 192 + c;
  float r[8];
#pragma unroll
  for (int j = 0; j < 8; j++)
    r[j] = fmaxf(di * a[j] + sw * sv[j] + bias[c + j], 0.f);
  *(uint4*)(out + (size_t)i * 192 + c) = pack8(r);
}

// ---------- segment softmax (gate f32, z bf16) ----------
__global__ void init_gmax_k(unsigned* __restrict__ gmaxu) {
  int t = blockIdx.x * 256 + threadIdx.x;
  if (t < NGRAPH * 192) gmaxu[t] = 0x007FFFFFu;
}

__global__ void seg_max_k(const float* __restrict__ gate, const int* __restrict__ gstart,
                          unsigned* __restrict__ gmaxu) {
  int g = blockIdx.x, f = threadIdx.x;
  int lo = gstart[g], hi = gstart[g + 1];
  int len = hi - lo;
  if (len <= 0) return;
  int per = (len + gridDim.y - 1) / gridDim.y;
  int a = lo + blockIdx.y * per;
  int b = min(a + per, hi);
  if (a >= b) return;
  float m = -INFINITY;
  for (int i = a; i < b; i++) m = fmaxf(m, gate[(size_t)i * 192 + f]);
  atomicMax(&gmaxu[g * 192 + f], flip_f(m));
}

__global__ void seg_sum_k(const float* __restrict__ gate, const unsigned short* __restrict__ z,
                          const int* __restrict__ gstart, const unsigned* __restrict__ gmaxu,
                          float* __restrict__ esum, float* __restrict__ znum) {
  int g = blockIdx.x, f = threadIdx.x;
  int lo = gstart[g], hi = gstart[g + 1];
  int len = hi - lo;
  if (len <= 0) return;
  int per = (len + gridDim.y - 1) / gridDim.y;
  int a = lo + blockIdx.y * per;
  int b = min(a + per, hi);
  if (a >= b) return;
  float gm = unflip_f(gmaxu[g * 192 + f]);
  float se = 0.f, sz = 0.f;
  for (int i = a; i < b; i++) {
    float e = expf(gate[(size_t)i * 192 + f] - gm);
    se += e;
    sz += e * bf2f(z[(size_t)i * 192 + f]);
  }
  atomicAdd(&esum[g * 192 + f], se);
  atomicAdd(&znum[g * 192 + f], sz);
}

__global__ void zg_fin_k(const float* __restrict__ znum, const float* __restrict__ esum,
                         float* __restrict__ zg) {
  int t = blockIdx.x * 256 + threadIdx.x;
  if (t >= NGRAPH * 192) return;
  float es = esum[t];
  zg[t] = (es > 0.f) ? znum[t] / es : 0.f;
}

// ---------- launch ----------
extern "C" void kernel_launch(void* const* d_in, const int* in_sizes, int n_in,
                              void* d_out, int out_size, void* d_ws, size_t ws_size,
                              hipStream_t stream) {
  const float* x1 = (const float*)d_in[0];
  const float* x2 = (const float*)d_in[1];
  const float* pe = (const float*)d_in[2];
  const int* ei = (const int*)d_in[3];
  const int* src = ei;
  const int* dst = ei + N_EDGES;
  const int* batch = (const int*)d_in[4];
  const float* Wc  = (const float*)d_in[5];  const float* bc  = (const float*)d_in[6];
  const float* Wmf = (const float*)d_in[7];  const float* bmf = (const float*)d_in[8];
  const float* Wgf = (const float*)d_in[9];  const float* bgf = (const float*)d_in[10];
  const float* Wmc = (const float*)d_in[11]; const float* bmc = (const float*)d_in[12];
  const float* Wgc = (const float*)d_in[13]; const float* bgc = (const float*)d_in[14];
  const float* Wa1 = (const float*)d_in[15]; const float* ba1 = (const float*)d_in[16];
  const float* Wa2 = (const float*)d_in[17]; const float* ba2 = (const float*)d_in[18];
  const float* Wgd = (const float*)d_in[19]; const float* bgd = (const float*)d_in[20];
  const float* Wd1 = (const float*)d_in[21]; const float* bd1 = (const float*)d_in[22];
  const float* Wd2 = (const float*)d_in[23]; const float* bd2 = (const float*)d_in[24];
  const float* Wd3 = (const float*)d_in[25]; const float* bd3 = (const float*)d_in[26];
  float* out = (float*)d_out;

  char* base = (char*)d_ws;
  size_t woff = 0;
  auto walloc = [&](size_t bytes) -> void* {
    void* p = base + woff;
    woff = (woff + bytes + 255) & ~(size_t)255;
    return p;
  };
  unsigned short* P0h = (unsigned short*)walloc((size_t)N_NODES * 192 * 2); // x1_res -> z
  unsigned short* P1h = (unsigned short*)walloc((size_t)N_NODES * 256 * 2); // h/h1/a1/t1
  unsigned short* P2h = (unsigned short*)walloc((size_t)N_NODES * 192 * 2); // agg/t0/agg_b/agg_c
  unsigned short* P5a = (unsigned short*)walloc((size_t)N_NODES * 32 * 2);
  unsigned short* P5b = (unsigned short*)walloc((size_t)N_NODES * 64 * 2);
  unsigned short* P5c = (unsigned short*)walloc((size_t)N_NODES * 64 * 2);
  float* Pg   = (float*)walloc((size_t)N_NODES * 192 * 4);                  // gate (f32)
  float* dinv = (float*)walloc((size_t)N_NODES * 4);
  unsigned* gmaxu = (unsigned*)walloc((size_t)NGRAPH * 192 * 4);
  float* esum = (float*)walloc((size_t)NGRAPH * 192 * 4);
  float* znum = (float*)walloc((size_t)NGRAPH * 192 * 4);
  float* zg   = (float*)walloc((size_t)NGRAPH * 192 * 4);
  float* zgW  = (float*)walloc((size_t)NGRAPH * 192 * 4);
  int* cnt      = (int*)walloc((size_t)N_NODES * 4);
  int* rowstart = (int*)walloc((size_t)N_NODES * 4);
  int* cursor   = (int*)walloc((size_t)N_NODES * 4);
  int* srcs     = (int*)walloc((size_t)N_EDGES * 4);
  int* bsum     = (int*)walloc(512 * 4);
  int* gstart   = (int*)walloc(80 * 4);

  unsigned short* P3h = (unsigned short*)d_out;                            // lower half scratch
  unsigned short* P4h = (unsigned short*)((float*)d_out + (size_t)N_NODES * 192); // upper half

  const int TB = 256;
  hipMemsetAsync(cnt, 0, N_NODES * sizeof(int), stream);
  hipMemsetAsync(esum, 0, 2 * NGRAPH * 192 * sizeof(float), stream);

  hist_k<<<(N_EDGES + TB - 1) / TB, TB, 0, stream>>>(dst, cnt);
  dinv_k<<<(N_NODES + TB - 1) / TB, TB, 0, stream>>>(cnt, dinv);
  int nb = (N_NODES + 255) / 256;
  scan_block_k<<<nb, 256, 0, stream>>>(cnt, rowstart, bsum);
  scan_bsum_k<<<1, 512, 0, stream>>>(bsum, nb);
  scan_add_k<<<nb, 256, 0, stream>>>(rowstart, cursor, bsum);
  build_k<<<(N_EDGES + TB - 1) / TB, TB, 0, stream>>>(src, dst, cursor, srcs);
  graph_starts_k<<<1, 128, 0, stream>>>(batch, gstart);

  const int mb128 = (N_NODES + 127) / 128;
  const int mb64 = (N_NODES + 63) / 64;
  const int ew24 = (N_NODES * 24 + TB - 1) / TB;
  const int ew8 = (N_NODES * 8 + TB - 1) / TB;

  // ---- encoder ----
  gemm_t<float, 2, 12, false><<<mb128, 256, 0, stream>>>(x1, Wc, bc, nullptr, nullptr, P0h, N_NODES, 384, 192, 1);
  add_pe3_bf<<<ew24, TB, 0, stream>>>(P0h, pe, P1h);
  agg_mpnn_bf<192><<<ew24, TB, 0, stream>>>(P1h, rowstart, cnt, srcs, P2h);
  gemm_t<unsigned short, 1, 16, false><<<mb64, 256, 0, stream>>>(P2h, Wmf, bmf, nullptr, nullptr, P1h, N_NODES, 192, 256, 1);
  gemm_t<unsigned short, 2, 12, false><<<mb128, 256, 0, stream>>>(P1h, Wgf, nullptr, nullptr, nullptr, P3h, N_NODES, 256, 192, 0);
  agg_gcn_bf<192, true, true><<<ew24, TB, 0, stream>>>(P3h, rowstart, cnt, srcs, dinv, bgf, P4h);
  agg_x2_k<<<ew8, TB, 0, stream>>>(x2, rowstart, cnt, srcs, P5a);
  gemm_t<unsigned short, 2, 4, false><<<mb128, 256, 0, stream>>>(P5a, Wmc, bmc, nullptr, nullptr, P5b, N_NODES, 32, 64, 1);
  agg_gcn_bf<64, false, false><<<ew8, TB, 0, stream>>>(P5b, rowstart, cnt, srcs, dinv, nullptr, P5c);
  // z = relu(cagg@Wgc + bgc) + h2 + x1_res  (in place over P0h)
  gemm_t<unsigned short, 2, 12, false><<<mb128, 256, 0, stream>>>(P5c, Wgc, bgc, P4h, P0h, P0h, N_NODES, 64, 192, 1);

  // ---- attention aggregation ----
  gemm_t<unsigned short, 1, 16, false><<<mb64, 256, 0, stream>>>(P0h, Wa1, ba1, nullptr, nullptr, P1h, N_NODES, 192, 256, 1);
  gemm_t<unsigned short, 2, 12, true><<<mb128, 256, 0, stream>>>(P1h, Wa2, ba2, nullptr, nullptr, Pg, N_NODES, 256, 192, 0);
  init_gmax_k<<<(NGRAPH * 192 + TB - 1) / TB, TB, 0, stream>>>(gmaxu);
  dim3 sg(NGRAPH, 16);
  seg_max_k<<<sg, 192, 0, stream>>>(Pg, gstart, gmaxu);
  seg_sum_k<<<sg, 192, 0, stream>>>(Pg, P0h, gstart, gmaxu, esum, znum);
  zg_fin_k<<<(NGRAPH * 192 + TB - 1) / TB, TB, 0, stream>>>(znum, esum, zg);
  gemm_kernel<<<dim3(1, 3), 256, 0, stream>>>(zg, Wgd, nullptr, zgW, NGRAPH, 192, 192);

  // ---- decoder ----
  agg_gcn_dec_bf<<<ew24, TB, 0, stream>>>(zgW, rowstart, cnt, srcs, batch, dinv, bgd, P4h);
  add_pe3_bf<<<ew24, TB, 0, stream>>>(P4h, pe, P2h);
  agg_mpnn_bf<192><<<ew24, TB, 0, stream>>>(P2h, rowstart, cnt, srcs, P3h);
  gemm_t<unsigned short, 2, 12, false><<<mb128, 256, 0, stream>>>(P3h, Wd1, bd1, nullptr, nullptr, P1h, N_NODES, 192, 192, 1);
  agg_mpnn_bf<192><<<ew24, TB, 0, stream>>>(P1h, rowstart, cnt, srcs, P2h);
  gemm_t<unsigned short, 2, 12, false><<<mb128, 256, 0, stream>>>(P2h, Wd2, bd2, P4h, nullptr, P3h, N_NODES, 192, 192, 1);
  agg_mpnn_bf<192><<<ew24, TB, 0, stream>>>(P3h, rowstart, cnt, srcs, P2h);
  gemm_t<unsigned short, 2, 12, true><<<dim3(mb128, 2), 256, 0, stream>>>(P2h, Wd3, bd3, nullptr, nullptr, out, N_NODES, 192, 384, 1);
  (void)in_sizes; (void)n_in; (void)out_size; (void)ws_size;
}